// Round 13
// baseline (286.140 us; speedup 1.0000x reference)
//
#include <hip/hip_runtime.h>
#include <hip/hip_fp16.h>
#include <math.h>

// GCN: 2x GraphConv(norm='both') + projection + softmax.
// N=100000 nodes, E=1600000 edges, feats 128 -> 64 -> 64 -> 8. All fp32 I/O.
//
// R12 post-mortem: gather latency-bound (1 node/wave, ~2 loads in flight,
// long shfl reduce) - VALU cuts didn't move it. R13: 4 nodes/wave (16 lanes
// each: 2 slots x 8 col-lanes), 32-edge prefetch, slot loop unrolled x8 ->
// up to 8 independent row loads in flight; reduce = 1 shfl stage. Projection
// +softmax fused into gather2 epilogue; wcvt folded into part. 8 dispatches.

#define NODES   100000
#define INF     128
#define HID     64
#define NLAB    8

#define SB      512                         // nodes per super-bucket
#define NSB     ((NODES + SB - 1) / SB)     // 196
#define NHALF   ((NODES + 255) / 256)       // 391 half-buckets (256 nodes)
#define CAP1    9000                        // per-sb edge cap (mean 8192, sigma~90)
#define SCAP    9000                        // per-sb src cap
#define CAP2    4600                        // per-half edge cap (mean 4096, sigma~64)
#define PCHUNK  4096                        // edges per part WG
#define PEPT    (PCHUNK / 256)              // 16
#define SRCMASK 0x1FFFF                     // 17 bits

union H8 { int4 i4; __half2 h2[4]; };

typedef _Float16 half8 __attribute__((ext_vector_type(8)));
typedef float floatx4 __attribute__((ext_vector_type(4)));

// ---------------- partition edges by dst>>9; src vals by src>>9 ----------------
// Blocks >= PB do the W fp16-transpose conversion instead (fused wcvt).

__global__ void part_kernel(const int* __restrict__ src, const int* __restrict__ dst,
                            int* __restrict__ gcur_d, int* __restrict__ gcur_s,
                            int* __restrict__ dreg, unsigned short* __restrict__ sreg,
                            const float* __restrict__ W1, const float* __restrict__ W2,
                            _Float16* __restrict__ wt1, _Float16* __restrict__ wt2,
                            int E, int PB) {
    __shared__ int hd[NSB], hs[NSB], bd[NSB], bs[NSB];
    const int tid = threadIdx.x;

    if (blockIdx.x >= PB) {                 // fused wcvt (2 blocks)
        const int N1 = 64 * (INF + 8);
        const int N2 = 64 * (HID + 8);
        for (int i = (blockIdx.x - PB) * 256 + tid; i < N1 + N2; i += 512) {
            if (i < N1) {
                int n = i / (INF + 8), k = i % (INF + 8);
                wt1[i] = (k < INF) ? (_Float16)W1[k * 64 + n] : (_Float16)0.f;
            } else {
                int j = i - N1;
                int n = j / (HID + 8), k = j % (HID + 8);
                wt2[j] = (k < HID) ? (_Float16)W2[k * 64 + n] : (_Float16)0.f;
            }
        }
        return;
    }

    const int e0 = blockIdx.x * PCHUNK;

    for (int i = tid; i < NSB; i += 256) { hd[i] = 0; hs[i] = 0; }
    __syncthreads();

    // phase A: LDS histograms; cache edges in registers
    int es[PEPT], ed[PEPT];
#pragma unroll
    for (int i = 0; i < PEPT; ++i) {
        int e = e0 + tid + i * 256;
        if (e < E) {
            es[i] = src[e]; ed[i] = dst[e];
            atomicAdd(&hd[ed[i] >> 9], 1);
            atomicAdd(&hs[es[i] >> 9], 1);
        } else es[i] = -1;
    }
    __syncthreads();

    // phase B: reserve contiguous runs (hot-line far atomics only: 392 addrs)
    for (int b = tid; b < NSB; b += 256) {
        int c = hd[b]; bd[b] = c ? atomicAdd(&gcur_d[b], c) : 0;
        c = hs[b];     bs[b] = c ? atomicAdd(&gcur_s[b], c) : 0;
    }
    __syncthreads();
    for (int b = tid; b < NSB; b += 256) { hd[b] = 0; hs[b] = 0; }
    __syncthreads();

    // phase C: scatter into runs (dst_local<<17 | src; src_local as ushort)
#pragma unroll
    for (int i = 0; i < PEPT; ++i) {
        if (es[i] >= 0) {
            int s = es[i], d = ed[i];
            int kb = d >> 9;
            int pos = bd[kb] + atomicAdd(&hd[kb], 1);
            if (pos < CAP1) dreg[(size_t)kb * CAP1 + pos] = ((d & (SB - 1)) << 17) | s;
            int ks = s >> 9;
            int ps = bs[ks] + atomicAdd(&hs[ks], 1);
            if (ps < SCAP) sreg[(size_t)ks * SCAP + ps] = (unsigned short)(s & (SB - 1));
        }
    }
}

// ---------------- src-degree histogram per super-bucket -> norm_s ----------------

__global__ void shist_kernel(const unsigned short* __restrict__ sreg,
                             const int* __restrict__ gcur_s,
                             float* __restrict__ norm_s, int Nn) {
    __shared__ int hist[SB];
    const int tid = threadIdx.x;
    const int sb = blockIdx.x;
    for (int i = tid; i < SB; i += 256) hist[i] = 0;
    __syncthreads();
    const int cnt = min(gcur_s[sb], SCAP);
    const unsigned short* base = sreg + (size_t)sb * SCAP;
    for (int i = tid; i < cnt; i += 256) atomicAdd(&hist[base[i]], 1);
    __syncthreads();
    for (int t = tid; t < SB; t += 256) {
        int node = sb * SB + t;
        if (node < Nn) norm_s[node] = rsqrtf(fmaxf((float)hist[t], 1.0f));
    }
}

// ---------------- per-half-bucket counting sort -> exact CSR ----------------

__global__ void csr2_kernel(const int* __restrict__ dreg, const int* __restrict__ gcur_d,
                            int* __restrict__ csr, int* __restrict__ starts,
                            int* __restrict__ ends, float* __restrict__ norm_d, int Nn) {
    __shared__ int hist[256], excl[256], cur[256];
    __shared__ int sorted[CAP2];
    __shared__ int tot_s;
    const int tid = threadIdx.x;
    const int j = blockIdx.x;
    const int sb = j >> 1, half = j & 1;
    const int cnt = min(gcur_d[sb], CAP1);
    const int* reg = dreg + (size_t)sb * CAP1;

    hist[tid] = 0;
    __syncthreads();

    for (int i = tid; i < cnt; i += 256) {
        int pe = reg[i];
        if (((pe >> 25) & 1) == half) atomicAdd(&hist[(pe >> 17) & 255], 1);
    }
    __syncthreads();

    excl[tid] = hist[tid];
    __syncthreads();
    for (int off = 1; off < 256; off <<= 1) {
        int v = (tid >= off) ? excl[tid - off] : 0;
        __syncthreads();
        excl[tid] += v;
        __syncthreads();
    }
    int deg = hist[tid];
    int st = excl[tid] - deg;
    if (tid == 255) tot_s = min(excl[255], CAP2);
    int node = j * 256 + tid;
    if (node < Nn) {
        int gs = j * CAP2 + st;
        int dcl = min(deg, max(CAP2 - st, 0));
        starts[node] = gs;
        ends[node]   = gs + dcl;
        norm_d[node] = rsqrtf(fmaxf((float)deg, 1.0f));
    }
    cur[tid] = st;
    __syncthreads();

    for (int i = tid; i < cnt; i += 256) {
        int pe = reg[i];
        if (((pe >> 25) & 1) == half) {
            int pos = atomicAdd(&cur[(pe >> 17) & 255], 1);
            if (pos < CAP2) sorted[pos] = pe & SRCMASK;
        }
    }
    __syncthreads();

    const int tot = tot_s;
    for (int i = tid; i < tot; i += 256) csr[(size_t)j * CAP2 + i] = sorted[i];
}

// ---------------- MFMA GEMM: Hh[row,:] = fp16( norm[row] * (X[row,:] @ W) ) ----------------

template <int K, bool IN16>
__global__ void gemm_mfma_kernel(const void* __restrict__ Xv, const float* __restrict__ norm,
                                 const _Float16* __restrict__ Wt, __half* __restrict__ Hh,
                                 int M) {
    constexpr int KP = K + 8;
    __shared__ _Float16 sWt[64 * KP];

    const int tid = threadIdx.x;
    constexpr int NI4 = 64 * KP * 2 / 16;
    for (int i = tid; i < NI4; i += 256)
        ((int4*)sWt)[i] = ((const int4*)Wt)[i];
    __syncthreads();

    const int w = tid >> 6, lane = tid & 63;
    const int m16 = lane & 15, quad = lane >> 4;
    const int rowA = blockIdx.x * 64 + w * 16 + m16;
    const int rowC = (rowA < M) ? rowA : (M - 1);

    floatx4 acc0 = {0.f, 0.f, 0.f, 0.f};
    floatx4 acc1 = acc0, acc2 = acc0, acc3 = acc0;

#pragma unroll
    for (int c = 0; c < K / 32; ++c) {
        const int k0 = c * 32 + quad * 8;
        half8 a;
        if constexpr (IN16) {
            const _Float16* xrow = (const _Float16*)Xv + (size_t)rowC * K;
            a = *(const half8*)(xrow + k0);
        } else {
            const float* xrow = (const float*)Xv + (size_t)rowC * K;
            float4 xa = *(const float4*)(xrow + k0);
            float4 xb = *(const float4*)(xrow + k0 + 4);
            a[0] = (_Float16)xa.x; a[1] = (_Float16)xa.y;
            a[2] = (_Float16)xa.z; a[3] = (_Float16)xa.w;
            a[4] = (_Float16)xb.x; a[5] = (_Float16)xb.y;
            a[6] = (_Float16)xb.z; a[7] = (_Float16)xb.w;
        }
        half8 b0 = *(const half8*)&sWt[(0 * 16 + m16) * KP + k0];
        half8 b1 = *(const half8*)&sWt[(1 * 16 + m16) * KP + k0];
        half8 b2 = *(const half8*)&sWt[(2 * 16 + m16) * KP + k0];
        half8 b3 = *(const half8*)&sWt[(3 * 16 + m16) * KP + k0];
        acc0 = __builtin_amdgcn_mfma_f32_16x16x32_f16(a, b0, acc0, 0, 0, 0);
        acc1 = __builtin_amdgcn_mfma_f32_16x16x32_f16(a, b1, acc1, 0, 0, 0);
        acc2 = __builtin_amdgcn_mfma_f32_16x16x32_f16(a, b2, acc2, 0, 0, 0);
        acc3 = __builtin_amdgcn_mfma_f32_16x16x32_f16(a, b3, acc3, 0, 0, 0);
    }

    const int rbase = blockIdx.x * 64 + w * 16 + quad * 4;
    floatx4 accs[4] = {acc0, acc1, acc2, acc3};
#pragma unroll
    for (int i = 0; i < 4; ++i) {
        int grow = rbase + i;
        if (grow < M) {
            float nm = norm[grow];
            __half* o = Hh + (size_t)grow * 64 + m16;
#pragma unroll
            for (int t = 0; t < 4; ++t)
                o[16 * t] = (__half)(accs[t][i] * nm);
        }
    }
}

// ---------------- pull gather, 4 nodes/wave, 8 loads in flight ----------------
// sub = lane>>4 (node within wave), g = (lane>>3)&1 (edge slot), c = lane&7
// (16B col chunk). 32-edge csr prefetch per node (2 coalesced loads); slot
// loop unrolled x8 -> 8 independent int4 row loads per iteration. All shfls
// at full exec (uniform mk = max over subs). Reduce = one xor-8 stage (both
// g-lanes end with the full row). PROJ: fused 64x8 projection + softmax.

template <bool PROJ>
__global__ void gather_kernel(const int* __restrict__ starts, const int* __restrict__ ends,
                              const int* __restrict__ csr, const __half* __restrict__ Hh,
                              const float* __restrict__ nd, const float* __restrict__ b,
                              const float* __restrict__ Wp, const float* __restrict__ bp,
                              __half* __restrict__ Xh, float* __restrict__ out, int Nn) {
    const int wid = blockIdx.x * 4 + (threadIdx.x >> 6);
    if (wid * 4 >= Nn) return;                  // wave-uniform
    const int lane = threadIdx.x & 63;
    const int sub = lane >> 4;                  // node within wave
    const int l16 = lane & 15;
    const int g = (lane >> 3) & 1;              // edge slot 0/1
    const int c = lane & 7;                     // 16B col chunk
    const int node = wid * 4 + sub;
    const bool nv = node < Nn;

    const int start = nv ? starts[node] : 0;
    const int end   = nv ? ends[node]   : 0;
    const int ec    = end - start;

    float acc[8] = {0.f, 0.f, 0.f, 0.f, 0.f, 0.f, 0.f, 0.f};

    for (int offs = 0; __any(offs < ec); offs += 32) {
        int i0 = offs + l16;
        int pe0 = (i0 < ec)      ? csr[start + i0]      : 0;
        int pe1 = (i0 + 16 < ec) ? csr[start + i0 + 16] : 0;
        int ecc = ec - offs;                    // may be <=0 for finished subs
        ecc = ecc < 0 ? 0 : (ecc > 32 ? 32 : ecc);
        int nk = (ecc + 1) >> 1;                // slot rounds (per sub)
        int mk = nk;
        mk = max(mk, __shfl_xor(mk, 16, 64));
        mk = max(mk, __shfl_xor(mk, 32, 64));   // uniform max over 4 subs

        for (int k = 0; k < mk; k += 8) {
            H8 v[8];
#pragma unroll
            for (int m = 0; m < 8; ++m) {
                int jb = 2 * (k + m);           // even, uniform
                int pe = (jb < 16) ? pe0 : pe1; // uniform register select
                int srcl = (lane & 48) + (jb & 15) + g;
                int s = __shfl(pe, srcl, 64);   // full-wave exec
                if (jb + g < ecc) v[m].i4 = ((const int4*)(Hh + (size_t)s * 64))[c];
                else              v[m].i4 = make_int4(0, 0, 0, 0);
            }
#pragma unroll
            for (int t = 0; t < 4; ++t) {
                __half2 s01 = __hadd2(v[0].h2[t], v[1].h2[t]);
                __half2 s23 = __hadd2(v[2].h2[t], v[3].h2[t]);
                __half2 s45 = __hadd2(v[4].h2[t], v[5].h2[t]);
                __half2 s67 = __hadd2(v[6].h2[t], v[7].h2[t]);
                __half2 s = __hadd2(__hadd2(s01, s23), __hadd2(s45, s67));
                float2 f = __half22float2(s);
                acc[2 * t]     += f.x;
                acc[2 * t + 1] += f.y;
            }
        }
    }

    // combine the two slot lanes (bit 3); both end with the full row
#pragma unroll
    for (int k = 0; k < 8; ++k)
        acc[k] += __shfl_xor(acc[k], 8, 64);

    const float nm = nv ? nd[node] : 0.f;
    float4 b0 = ((const float4*)b)[2 * c];
    float4 b1 = ((const float4*)b)[2 * c + 1];
    float r[8];
    r[0] = fmaxf(fmaf(acc[0], nm, b0.x), 0.f);
    r[1] = fmaxf(fmaf(acc[1], nm, b0.y), 0.f);
    r[2] = fmaxf(fmaf(acc[2], nm, b0.z), 0.f);
    r[3] = fmaxf(fmaf(acc[3], nm, b0.w), 0.f);
    r[4] = fmaxf(fmaf(acc[4], nm, b1.x), 0.f);
    r[5] = fmaxf(fmaf(acc[5], nm, b1.y), 0.f);
    r[6] = fmaxf(fmaf(acc[6], nm, b1.z), 0.f);
    r[7] = fmaxf(fmaf(acc[7], nm, b1.w), 0.f);

    if constexpr (!PROJ) {
        if (g == 0 && nv) {
            H8 o;
            o.h2[0] = __floats2half2_rn(r[0], r[1]);
            o.h2[1] = __floats2half2_rn(r[2], r[3]);
            o.h2[2] = __floats2half2_rn(r[4], r[5]);
            o.h2[3] = __floats2half2_rn(r[6], r[7]);
            ((int4*)(Xh + (size_t)node * 64))[c] = o.i4;
        }
    } else {
        // fused projection: partial logits over this lane's 8 cols (k = 8c+i)
        float lg[8] = {0.f, 0.f, 0.f, 0.f, 0.f, 0.f, 0.f, 0.f};
#pragma unroll
        for (int i = 0; i < 8; ++i) {
            float4 wA = ((const float4*)Wp)[(c * 8 + i) * 2];
            float4 wB = ((const float4*)Wp)[(c * 8 + i) * 2 + 1];
            lg[0] = fmaf(r[i], wA.x, lg[0]); lg[1] = fmaf(r[i], wA.y, lg[1]);
            lg[2] = fmaf(r[i], wA.z, lg[2]); lg[3] = fmaf(r[i], wA.w, lg[3]);
            lg[4] = fmaf(r[i], wB.x, lg[4]); lg[5] = fmaf(r[i], wB.y, lg[5]);
            lg[6] = fmaf(r[i], wB.z, lg[6]); lg[7] = fmaf(r[i], wB.w, lg[7]);
        }
#pragma unroll
        for (int m = 1; m <= 4; m <<= 1)
#pragma unroll
            for (int l = 0; l < 8; ++l)
                lg[l] += __shfl_xor(lg[l], m, 64);   // reduce over c (bits 0-2)
        if ((lane & 15) == 0 && nv) {                // one lane per node
            float logit[8];
#pragma unroll
            for (int l = 0; l < 8; ++l) logit[l] = lg[l] + bp[l];
            float mx = logit[0];
#pragma unroll
            for (int l = 1; l < 8; ++l) mx = fmaxf(mx, logit[l]);
            float s = 0.f;
#pragma unroll
            for (int l = 0; l < 8; ++l) { logit[l] = __expf(logit[l] - mx); s += logit[l]; }
            float inv = 1.f / s;
            float4 o0 = make_float4(logit[0] * inv, logit[1] * inv, logit[2] * inv, logit[3] * inv);
            float4 o1 = make_float4(logit[4] * inv, logit[5] * inv, logit[6] * inv, logit[7] * inv);
            ((float4*)(out + (size_t)node * 8))[0] = o0;
            ((float4*)(out + (size_t)node * 8))[1] = o1;
        }
    }
}

// ---------------- launch ----------------

extern "C" void kernel_launch(void* const* d_in, const int* in_sizes, int n_in,
                              void* d_out, int out_size, void* d_ws, size_t ws_size,
                              hipStream_t stream) {
    const float* features = (const float*)d_in[0];
    const int*   edge_src = (const int*)d_in[1];
    const int*   edge_dst = (const int*)d_in[2];
    const float* W1 = (const float*)d_in[4];
    const float* b1 = (const float*)d_in[5];
    const float* W2 = (const float*)d_in[6];
    const float* b2 = (const float*)d_in[7];
    const float* Wp = (const float*)d_in[8];
    const float* bp = (const float*)d_in[9];
    float* out = (float*)d_out;

    const int N = NODES;
    const int E = in_sizes[1];
    const int PB = (E + PCHUNK - 1) / PCHUNK;   // 391 partition blocks

    // ---- workspace layout (~35 MB; dreg/sreg alias h, dead before gemm1) ----
    char* p = (char*)d_ws;
    int*   csr    = (int*)p;            p += sizeof(int) * (size_t)NHALF * CAP2;  // 7.2 MB
    int*   starts = (int*)p;            p += sizeof(int) * N;
    int*   ends   = (int*)p;            p += sizeof(int) * N;
    float* norm_s = (float*)p;          p += sizeof(float) * N;
    float* norm_d = (float*)p;          p += sizeof(float) * N;
    int*   gcur_d = (int*)p;            p += sizeof(int) * NSB;        // zeroed
    int*   gcur_s = (int*)p;            p += sizeof(int) * NSB;        // zeroed
    p = (char*)(((size_t)p + 255) & ~(size_t)255);
    _Float16* wt1 = (_Float16*)p;       p += sizeof(_Float16) * 64 * (INF + 8);
    _Float16* wt2 = (_Float16*)p;       p += sizeof(_Float16) * 64 * (HID + 8);
    p = (char*)(((size_t)p + 255) & ~(size_t)255);
    __half* h     = (__half*)p;         p += sizeof(__half) * (size_t)N * 64; // 12.8 MB
    p = (char*)(((size_t)p + 255) & ~(size_t)255);
    __half* x     = (__half*)p;         p += sizeof(__half) * (size_t)N * 64; // 12.8 MB
    // aliases inside h (consumed by shist/csr2 before gemm1 writes h):
    int*            dreg = (int*)h;                                          // 7.06 MB
    unsigned short* sreg = (unsigned short*)((char*)h + sizeof(int) * (size_t)NSB * CAP1); // 3.5 MB

    hipMemsetAsync(gcur_d, 0, sizeof(int) * 2 * NSB, stream);

    // ---- build: partition (+fused W convert) -> src histogram -> exact CSR ----
    part_kernel<<<PB + 2, 256, 0, stream>>>(edge_src, edge_dst, gcur_d, gcur_s,
                                            dreg, sreg, W1, W2, wt1, wt2, E, PB);
    shist_kernel<<<NSB, 256, 0, stream>>>(sreg, gcur_s, norm_s, N);
    csr2_kernel<<<NHALF, 256, 0, stream>>>(dreg, gcur_d, csr, starts, ends, norm_d, N);

    // ---- layer 1 ----
    gemm_mfma_kernel<INF, false><<<(N + 63) / 64, 256, 0, stream>>>(features, norm_s, wt1, h, N);
    gather_kernel<false><<<(N + 15) / 16, 256, 0, stream>>>(starts, ends, csr, h, norm_d,
                                                            b1, nullptr, nullptr, x, nullptr, N);

    // ---- layer 2 (+fused projection/softmax) ----
    gemm_mfma_kernel<HID, true><<<(N + 63) / 64, 256, 0, stream>>>(x, norm_s, wt2, h, N);
    gather_kernel<true><<<(N + 15) / 16, 256, 0, stream>>>(starts, ends, csr, h, norm_d,
                                                           b2, Wp, bp, nullptr, out, N);
}